// Round 1
// baseline (562.342 us; speedup 1.0000x reference)
//
#include <hip/hip_runtime.h>

// QLSTM recurrence on MI355X — round 4.
// Structural change: ONE wave (64 threads) per batch element, each lane owns
// 4 consecutive h indices (g = 4l+k). The 384-wide y-reduce becomes fully
// wave-local (packed per-lane FMA + 6-level DPP tree + readlane), eliminating
// the cross-wave LDS round trip (ds_write + lgkm drain + s_barrier + 4x
// ds_read_b128 + combine) that sat on the serial chain every step (~300-400
// cyc). Added per-lane gate work (4x activations, 4x z-dots) is paid back
// with float2/v_pk_* packing and merged-rcp gate algebra:
//   i*g = (E2-1) * rcp((1+e0)(1+E2)),  o*tanh(c) = (Ec-1)*rcp((1+e3)(1+Ec))
// (8 trans per h instead of 10; exact re-association, |c|~O(1) so no inf path).
// Loop has NO barriers and NO LDS; only waits are prefetched-x vmcnt and
// compiler-handled DPP hazards.

#define B_ 256
#define T_ 512
#define F_ 128
#define H_ 256

typedef float f2 __attribute__((ext_vector_type(2)));

__device__ __forceinline__ float rcp_f(float x)  { return __builtin_amdgcn_rcpf(x); }
__device__ __forceinline__ float exp2_f(float x) { return __builtin_amdgcn_exp2f(x); }

__device__ __forceinline__ float tanh_f(float x) {
    return 1.0f - 2.0f * rcp_f(1.0f + exp2_f(2.885390082f * x));
}

__device__ __forceinline__ f2 splat2(float s) { f2 v; v.x = s; v.y = s; return v; }

__device__ __forceinline__ float rl(float v, int lane) {
    return __int_as_float(__builtin_amdgcn_readlane(__float_as_int(v), lane));
}

// One DPP butterfly level applied to both halves of a packed pair.
template<int CTRL>
__device__ __forceinline__ f2 dpp_add2(f2 v) {
    int lo = __builtin_amdgcn_update_dpp(0, __float_as_int(v.x), CTRL, 0xf, 0xf, true);
    int hi = __builtin_amdgcn_update_dpp(0, __float_as_int(v.y), CTRL, 0xf, 0xf, true);
    f2 p; p.x = __int_as_float(lo); p.y = __int_as_float(hi);
    return v + p;
}

// 64-lane sum of both packed halves; result valid at LANE 63 only.
__device__ __forceinline__ f2 wave_sum2_63(f2 v) {
    v = dpp_add2<0xB1>(v);    // xor 1 (quad_perm)
    v = dpp_add2<0x4E>(v);    // xor 2 (quad_perm)
    v = dpp_add2<0x141>(v);   // row_half_mirror
    v = dpp_add2<0x140>(v);   // row_mirror
    v = dpp_add2<0x142>(v);   // row_bcast15
    v = dpp_add2<0x143>(v);   // row_bcast31
    return v;
}

// Per-h gate block with merged reciprocals: returns new h, updates c.
// i = 1/(1+e0), f = 1/(1+e1), g = (E2-1)/(E2+1), o = 1/(1+e3)
// i*g and o*tanh(c) each use a single rcp of the product of denominators.
__device__ __forceinline__ float lstm_gate(float zi, float zf, float zg, float zo,
                                           float& c) {
    const float e0 = exp2_f(-1.442695041f * zi);
    const float e1 = exp2_f(-1.442695041f * zf);
    const float E2 = exp2_f( 2.885390082f * zg);
    const float e3 = exp2_f(-1.442695041f * zo);
    const float ig = (E2 - 1.0f) * rcp_f((1.0f + e0) * (1.0f + E2));
    const float fg = rcp_f(1.0f + e1);
    c = fmaf(fg, c, ig);
    const float Ec = exp2_f(2.885390082f * c);
    return (Ec - 1.0f) * rcp_f((1.0f + e3) * (1.0f + Ec));
}

__global__ __launch_bounds__(64, 1) void qlstm_kernel(
    const float* __restrict__ x,      // [B,T,F]
    const float* __restrict__ W_in,   // [H+F, 4] (row = float4)
    const float* __restrict__ b_in,   // [4]
    const float* __restrict__ Wq,     // [4,4,4]
    const float* __restrict__ bq,     // [4,4]
    const float* __restrict__ W_out,  // [4,H]
    const float* __restrict__ b_out,  // [H]
    float* __restrict__ out)          // [B*T*H] ++ [B*H] ++ [B*H]
{
    const int b = blockIdx.x;
    const int l = threadIdx.x;        // 0..63 — owns h indices 4l..4l+3

    const float4* Win4 = (const float4*)W_in;

    // W_in rows for my 4 h indices, split into q-pairs (q01 / q23).
    f2 wh01[4], wh23[4];
#pragma unroll
    for (int k = 0; k < 4; ++k) {
        float4 r = Win4[4 * l + k];
        wh01[k].x = r.x; wh01[k].y = r.y;
        wh23[k].x = r.z; wh23[k].y = r.w;
    }
    // W_in rows for my 2 x indices (j = 2l, 2l+1).
    float4 ra = Win4[H_ + 2 * l];
    float4 rb = Win4[H_ + 2 * l + 1];
    f2 wxa01; wxa01.x = ra.x; wxa01.y = ra.y;
    f2 wxa23; wxa23.x = ra.z; wxa23.y = ra.w;
    f2 wxb01; wxb01.x = rb.x; wxb01.y = rb.y;
    f2 wxb23; wxb23.x = rb.z; wxb23.y = rb.w;

    // W_out columns for my 4 h indices, as h-pairs per r.
    f2 wo01[4], wo23[4];
#pragma unroll
    for (int r = 0; r < 4; ++r) {
        float4 t = *(const float4*)(W_out + r * H_ + 4 * l);
        wo01[r].x = t.x; wo01[r].y = t.y;
        wo23[r].x = t.z; wo23[r].y = t.w;
    }
    float4 bo4 = *(const float4*)(b_out + 4 * l);
    f2 bo01; bo01.x = bo4.x; bo01.y = bo4.y;
    f2 bo23; bo23.x = bo4.z; bo23.y = bo4.w;

    float bin[4];
#pragma unroll
    for (int q = 0; q < 4; ++q) bin[q] = b_in[q];

    // Lane-distributed q-block: lane m=l&15 owns (k,r)=(m>>2, m&3).
    const int m = l & 15, qk = m >> 2, qr = m & 3;
    float wql[4];
#pragma unroll
    for (int s = 0; s < 4; ++s) wql[s] = Wq[qk * 16 + s * 4 + qr];
    float bql = bq[qk * 4 + qr];
#pragma unroll
    for (int s = 0; s < 4; ++s) bql = fmaf(bin[s], wql[s], bql);  // fold b_in

    float h0 = 0.f, h1 = 0.f, h2 = 0.f, h3 = 0.f;
    float c0 = 0.f, c1 = 0.f, c2 = 0.f, c3 = 0.f;

    const float* xp = x + (size_t)b * T_ * F_ + 2 * l;
    f2 xv = *(const f2*)xp;   // x[t=0], my 2 elements

    float4* o4 = (float4*)(out + (size_t)b * T_ * H_) + l;

    for (int t = 0; t < T_; ++t) {
        const f2 xc = xv;
        const int tn = (t + 1 < T_) ? (t + 1) : t;
        xv = *(const f2*)(xp + (size_t)tn * F_);   // prefetch, off-chain

        // Per-lane partials: 4 h + 2 x contributions, two balanced chains.
        f2 A01 = splat2(xc.x) * wxa01;
        f2 A23 = splat2(xc.x) * wxa23;
        f2 B01 = splat2(xc.y) * wxb01;
        f2 B23 = splat2(xc.y) * wxb23;
        A01 = splat2(h0) * wh01[0] + A01;
        A23 = splat2(h0) * wh23[0] + A23;
        A01 = splat2(h1) * wh01[1] + A01;
        A23 = splat2(h1) * wh23[1] + A23;
        B01 = splat2(h2) * wh01[2] + B01;
        B23 = splat2(h2) * wh23[2] + B23;
        B01 = splat2(h3) * wh01[3] + B01;
        B23 = splat2(h3) * wh23[3] + B23;

        // Wave-local 64-lane reduce (no LDS, no barrier).
        f2 s01 = wave_sum2_63(A01 + B01);
        f2 s23 = wave_sum2_63(A23 + B23);
        const float y0 = rl(s01.x, 63);
        const float y1 = rl(s01.y, 63);
        const float y2 = rl(s23.x, 63);
        const float y3 = rl(s23.y, 63);

        // q block: every lane computes its m's value; broadcast via readlane.
        float aq = bql;
        aq = fmaf(y0, wql[0], aq);
        aq = fmaf(y1, wql[1], aq);
        aq = fmaf(y2, wql[2], aq);
        aq = fmaf(y3, wql[3], aq);
        const float qown = tanh_f(aq);
        float qs[16];
#pragma unroll
        for (int i = 0; i < 16; ++i) qs[i] = rl(qown, i);

        // z[k] for my 4 h indices, packed over h-pairs.
        f2 z01[4] = {bo01, bo01, bo01, bo01};
        f2 z23[4] = {bo23, bo23, bo23, bo23};
#pragma unroll
        for (int r = 0; r < 4; ++r) {
#pragma unroll
            for (int k = 0; k < 4; ++k) {
                const f2 qsp = splat2(qs[k * 4 + r]);
                z01[k] = qsp * wo01[r] + z01[k];
                z23[k] = qsp * wo23[r] + z23[k];
            }
        }

        // Gates (i=z0, f=z1, g=z2, o=z3), 4 independent chains -> pipelined.
        h0 = lstm_gate(z01[0].x, z01[1].x, z01[2].x, z01[3].x, c0);
        h1 = lstm_gate(z01[0].y, z01[1].y, z01[2].y, z01[3].y, c1);
        h2 = lstm_gate(z23[0].x, z23[1].x, z23[2].x, z23[3].x, c2);
        h3 = lstm_gate(z23[0].y, z23[1].y, z23[2].y, z23[3].y, c3);

        // One coalesced 16B store per lane; vmcnt never drained in-loop.
        o4[(size_t)t * (H_ / 4)] = make_float4(h0, h1, h2, h3);
    }

    float* hT = out + (size_t)B_ * T_ * H_;
    *(float4*)(hT + (size_t)b * H_ + 4 * l) = make_float4(h0, h1, h2, h3);
    *(float4*)(hT + (size_t)B_ * H_ + (size_t)b * H_ + 4 * l) =
        make_float4(c0, c1, c2, c3);
}

extern "C" void kernel_launch(void* const* d_in, const int* in_sizes, int n_in,
                              void* d_out, int out_size, void* d_ws, size_t ws_size,
                              hipStream_t stream) {
    const float* x     = (const float*)d_in[0];
    const float* W_in  = (const float*)d_in[1];
    const float* b_in  = (const float*)d_in[2];
    const float* Wq    = (const float*)d_in[3];
    const float* bq    = (const float*)d_in[4];
    const float* W_out = (const float*)d_in[5];
    const float* b_out = (const float*)d_in[6];
    float* out = (float*)d_out;

    qlstm_kernel<<<dim3(B_), dim3(64), 0, stream>>>(
        x, W_in, b_in, Wq, bq, W_out, b_out, out);
}

// Round 2
// 387.485 us; speedup vs baseline: 1.4513x; 1.4513x over previous
//
#include <hip/hip_runtime.h>

// QLSTM recurrence on MI355X — round 5.
// Structure = round 3 (best so far): 256 blocks x 256 threads, one block per
// batch element, 4 waves on 4 SIMDs, lane g owns h index g, per-wave DPP
// reduce + LDS exchange of y-partials, lane-distributed q-tanh + readlane
// broadcast, raw lgkm-only barrier (vmcnt never drained in-loop).
//
// Round-4 lesson (reverted): consolidating to 1 wave quadruples per-SIMD
// transcendental issue (trans = quarter rate, wave64 ops don't scale down
// with active lanes) -> 425 us. Gate work must stay spread over 4 SIMDs.
//
// Round-5 trims (each validated numerically in round 4, absmax 0.00098):
//  - merged-rcp gates: i*g=(E2-1)*rcp((1+e0)(1+E2)), o*tanh(c)=(Ec-1)*rcp(
//    (1+e3)(1+Ec)): 12 -> 10 trans per lane-step.
//  - pre-scaled weights: fold +-log2(e) into W_out/b_out (per-gate), Wq/bq;
//    carry C = 2*log2(e)*c so Ec = exp2(C) directly — no mul feeds any exp2.
//  - packed f2 combine of the 4 LDS partials (6 pk_add vs 12 adds).
//  - balanced depth-3 trees for aq and z dots.
//  - x prefetch distance 2 (store never enters the xv vmcnt wait).

#define B_ 256
#define T_ 512
#define F_ 128
#define H_ 256

#define SC1 1.442695041f    // log2(e)
#define SC2 2.885390082f    // 2*log2(e)
#define ISC2 0.3465735903f  // 1/SC2

typedef float f2 __attribute__((ext_vector_type(2)));

__device__ __forceinline__ float rcp_f(float x)  { return __builtin_amdgcn_rcpf(x); }
__device__ __forceinline__ float exp2_f(float x) { return __builtin_amdgcn_exp2f(x); }

__device__ __forceinline__ f2 mk2(float a, float b) { f2 v; v.x = a; v.y = b; return v; }

__device__ __forceinline__ float rl(float v, int lane) {
    return __int_as_float(__builtin_amdgcn_readlane(__float_as_int(v), lane));
}

template<int CTRL>
__device__ __forceinline__ float dpp_add(float v) {
    int p = __builtin_amdgcn_update_dpp(0, __float_as_int(v), CTRL, 0xf, 0xf, true);
    return v + __int_as_float(p);
}

// 64-lane sum; result valid at LANE 63 only.
__device__ __forceinline__ float wave_sum63(float v) {
    v = dpp_add<0xB1>(v);    // xor 1
    v = dpp_add<0x4E>(v);    // xor 2
    v = dpp_add<0x141>(v);   // row_half_mirror
    v = dpp_add<0x140>(v);   // row_mirror
    v = dpp_add<0x142>(v);   // row_bcast15
    v = dpp_add<0x143>(v);   // row_bcast31
    return v;
}

// LDS-only barrier: drain LDS ops, sync waves. Does NOT drain vmcnt — global
// stores/prefetches stay in flight across it.
__device__ __forceinline__ void lds_barrier() {
    asm volatile("s_waitcnt lgkmcnt(0)\n\ts_barrier" ::: "memory");
}

__global__ __launch_bounds__(256, 1) void qlstm_kernel(
    const float* __restrict__ x,      // [B,T,F]
    const float* __restrict__ W_in,   // [H+F, 4] (row = float4)
    const float* __restrict__ b_in,   // [4]
    const float* __restrict__ Wq,     // [4,4,4]
    const float* __restrict__ bq,     // [4,4]
    const float* __restrict__ W_out,  // [4,H]
    const float* __restrict__ b_out,  // [H]
    float* __restrict__ out)          // [B*T*H] ++ [B*H] ++ [B*H]
{
    const int b = blockIdx.x;
    const int g = threadIdx.x;   // 0..255 — my h index
    const int w = g >> 6;        // wave 0..3
    const int l = g & 63;

    __shared__ float4 part[2][4];  // [t&1][wave] y-partials

    const float4* Win4 = (const float4*)W_in;

    float4 t4 = Win4[g];
    float wh[4] = {t4.x, t4.y, t4.z, t4.w};

    const bool has_x = (w < 2);
    float wx[4] = {0.f, 0.f, 0.f, 0.f};
    if (has_x) {
        float4 u4 = Win4[H_ + g];
        wx[0] = u4.x; wx[1] = u4.y; wx[2] = u4.z; wx[3] = u4.w;
    }

    // Per-gate pre-scaled W_out columns / b_out: gate k's z is computed
    // already multiplied by sk[k], so exp2 consumes it directly.
    const float sk[4] = {-SC1, -SC1, SC2, -SC1};
    float wo_k[4][4];
    float bo_k[4];
    {
        const float bo = b_out[g];
#pragma unroll
        for (int r = 0; r < 4; ++r) {
            const float wor = W_out[r * H_ + g];
#pragma unroll
            for (int k = 0; k < 4; ++k) wo_k[k][r] = wor * sk[k];
        }
#pragma unroll
        for (int k = 0; k < 4; ++k) bo_k[k] = bo * sk[k];
    }

    float bin[4];
#pragma unroll
    for (int q = 0; q < 4; ++q) bin[q] = b_in[q];

    // Lane-distributed q-block: lane m=l&15 owns (k,r)=(m>>2, m&3).
    // Weights pre-scaled by SC2 so qown = 1 - 2*rcp(1+exp2(aq)).
    const int m = l & 15, qk = m >> 2, qr = m & 3;
    float wql[4];
#pragma unroll
    for (int s = 0; s < 4; ++s) wql[s] = Wq[qk * 16 + s * 4 + qr];
    float bql = bq[qk * 4 + qr];
#pragma unroll
    for (int s = 0; s < 4; ++s) bql = fmaf(bin[s], wql[s], bql);  // fold b_in
    bql *= SC2;
#pragma unroll
    for (int s = 0; s < 4; ++s) wql[s] *= SC2;

    float h = 0.f;
    float C = 0.f;   // scaled cell state: C = SC2 * c

    const float* xp = x + (size_t)b * T_ * F_ + g;
    // Prefetch distance 2: the xv vmcnt wait never has to cover the h-store.
    float xb0 = has_x ? xp[0] : 0.f;
    float xb1 = has_x ? xp[F_] : 0.f;

    float* outp = out + (size_t)b * T_ * H_ + g;

    for (int t = 0; t < T_; ++t) {
        const float xc = xb0;
        xb0 = xb1;
        if (has_x) {
            int tn = (t + 2 < T_) ? (t + 2) : (T_ - 1);
            xb1 = xp[(size_t)tn * F_];   // stays in flight across barriers
        }

        // x-part is h-independent: computed off the serial chain.
        const float xq0 = xc * wx[0];
        const float xq1 = xc * wx[1];
        const float xq2 = xc * wx[2];
        const float xq3 = xc * wx[3];

        float p0 = fmaf(h, wh[0], xq0);
        float p1 = fmaf(h, wh[1], xq1);
        float p2 = fmaf(h, wh[2], xq2);
        float p3 = fmaf(h, wh[3], xq3);
        p0 = wave_sum63(p0);
        p1 = wave_sum63(p1);
        p2 = wave_sum63(p2);
        p3 = wave_sum63(p3);
        if (l == 63) part[t & 1][w] = make_float4(p0, p1, p2, p3);
        lds_barrier();
        const float4 a0 = part[t & 1][0];
        const float4 a1 = part[t & 1][1];
        const float4 a2 = part[t & 1][2];
        const float4 a3 = part[t & 1][3];
        // Packed combine: 6 pk_adds instead of 12 scalar adds.
        const f2 y01 = (mk2(a0.x, a0.y) + mk2(a1.x, a1.y)) +
                       (mk2(a2.x, a2.y) + mk2(a3.x, a3.y));
        const f2 y23 = (mk2(a0.z, a0.w) + mk2(a1.z, a1.w)) +
                       (mk2(a2.z, a2.w) + mk2(a3.z, a3.w));
        const float y0 = y01.x, y1 = y01.y, y2 = y23.x, y3 = y23.y;

        // aq (pre-scaled by SC2), balanced depth-3 tree.
        float u = fmaf(y0, wql[0], bql);
        const float v = fmaf(y2, wql[2], y1 * wql[1]);
        u = fmaf(y3, wql[3], u);
        const float aq = u + v;
        const float qown = 1.0f - 2.0f * rcp_f(1.0f + exp2_f(aq));

        float qs[16];
#pragma unroll
        for (int i = 0; i < 16; ++i) qs[i] = rl(qown, i);

        // z'[k] = sk[k] * z[k] via pre-scaled weights; balanced trees.
        float zp[4];
#pragma unroll
        for (int k = 0; k < 4; ++k) {
            float a = fmaf(qs[k * 4 + 0], wo_k[k][0], bo_k[k]);
            const float bsum = fmaf(qs[k * 4 + 1], wo_k[k][1],
                                    qs[k * 4 + 2] * wo_k[k][2]);
            a = fmaf(qs[k * 4 + 3], wo_k[k][3], a);
            zp[k] = a + bsum;
        }

        // Merged-rcp gates on pre-scaled z':
        //   e0=exp(-zi) e1=exp(-zf) E2=exp(2 zg) e3=exp(-zo)
        //   C' = fg*C + SC2*i*g ;  h = (Ec-1)*rcp((1+e3)(1+Ec)), Ec=exp2(C')
        const float e0 = exp2_f(zp[0]);
        const float e1 = exp2_f(zp[1]);
        const float E2 = exp2_f(zp[2]);
        const float e3 = exp2_f(zp[3]);
        const float num2 = fmaf(SC2, E2, -SC2);           // SC2*(E2-1)
        const float IG2  = num2 * rcp_f((1.0f + e0) * (1.0f + E2));
        const float fg   = rcp_f(1.0f + e1);
        C = fmaf(fg, C, IG2);
        const float Ec = exp2_f(C);
        h = (Ec - 1.0f) * rcp_f((1.0f + e3) * (1.0f + Ec));

        outp[(size_t)t * H_] = h;  // floats free past the raw barrier
    }

    float* hT = out + (size_t)B_ * T_ * H_;
    hT[(size_t)b * H_ + g] = h;
    hT[(size_t)B_ * H_ + (size_t)b * H_ + g] = C * ISC2;
}

extern "C" void kernel_launch(void* const* d_in, const int* in_sizes, int n_in,
                              void* d_out, int out_size, void* d_ws, size_t ws_size,
                              hipStream_t stream) {
    const float* x     = (const float*)d_in[0];
    const float* W_in  = (const float*)d_in[1];
    const float* b_in  = (const float*)d_in[2];
    const float* Wq    = (const float*)d_in[3];
    const float* bq    = (const float*)d_in[4];
    const float* W_out = (const float*)d_in[5];
    const float* b_out = (const float*)d_in[6];
    float* out = (float*)d_out;

    qlstm_kernel<<<dim3(B_), dim3(256), 0, stream>>>(
        x, W_in, b_in, Wq, bq, W_out, b_out, out);
}

// Round 3
// 369.862 us; speedup vs baseline: 1.5204x; 1.0476x over previous
//
#include <hip/hip_runtime.h>

// QLSTM recurrence on MI355X — round 6.
// Structure = round 5 (4 waves on 4 SIMDs, lane g owns h index g, per-wave
// reduce + LDS exchange of y-partials, lane-distributed q-tanh + readlane
// broadcast, raw lgkm-only barrier, merged-rcp pre-scaled gates).
//
// Round-6 changes (chain is stall-dominated: 1193 cyc/step, ~700 stall):
//  1. DPP tree fused to 24 v_add_f32_dpp (was 48 mov_dpp+add). Chains
//     interleaved so each DPP consumer is >=4 instrs from its producer
//     (VALU->DPP hazard satisfied by construction; s_nop 1 entry guard).
//  2. Post-barrier LDS-read window (~120 cyc dead) filled: next-step x*Wx
//     multiplies + x prefetch issue moved between ds_read issue and combine.
//  3. Manual unroll x2: compile-time slot index, half the loop overhead.

#define B_ 256
#define T_ 512
#define F_ 128
#define H_ 256

#define SC1 1.442695041f    // log2(e)
#define SC2 2.885390082f    // 2*log2(e)
#define ISC2 0.3465735903f  // 1/SC2

typedef float f2 __attribute__((ext_vector_type(2)));

__device__ __forceinline__ float rcp_f(float x)  { return __builtin_amdgcn_rcpf(x); }
__device__ __forceinline__ float exp2_f(float x) { return __builtin_amdgcn_exp2f(x); }

__device__ __forceinline__ f2 mk2(float a, float b) { f2 v; v.x = a; v.y = b; return v; }

__device__ __forceinline__ float rl(float v, int lane) {
    return __int_as_float(__builtin_amdgcn_readlane(__float_as_int(v), lane));
}

// Fused 64-lane sum of 4 independent values; results valid at LANE 63 only.
// 6 levels x 4 interleaved chains: consumer-producer distance = 4 instrs,
// covering the VALU->DPP 2-wait-state hazard by construction. s_nop 1 covers
// the entry hazard (p fmas immediately before). In-place src0==src1==dst is
// legal (DPP gathers old value before write). bound_ctrl omitted: all perm
// sources are valid under full exec; bcast rows without sources keep their
// old value, which only affects lanes we never read.
__device__ __forceinline__ void tree4(float& p0, float& p1, float& p2, float& p3) {
    asm volatile(
        "s_nop 1\n\t"
        "v_add_f32_dpp %0, %0, %0 quad_perm:[1,0,3,2] row_mask:0xf bank_mask:0xf\n\t"
        "v_add_f32_dpp %1, %1, %1 quad_perm:[1,0,3,2] row_mask:0xf bank_mask:0xf\n\t"
        "v_add_f32_dpp %2, %2, %2 quad_perm:[1,0,3,2] row_mask:0xf bank_mask:0xf\n\t"
        "v_add_f32_dpp %3, %3, %3 quad_perm:[1,0,3,2] row_mask:0xf bank_mask:0xf\n\t"
        "v_add_f32_dpp %0, %0, %0 quad_perm:[2,3,0,1] row_mask:0xf bank_mask:0xf\n\t"
        "v_add_f32_dpp %1, %1, %1 quad_perm:[2,3,0,1] row_mask:0xf bank_mask:0xf\n\t"
        "v_add_f32_dpp %2, %2, %2 quad_perm:[2,3,0,1] row_mask:0xf bank_mask:0xf\n\t"
        "v_add_f32_dpp %3, %3, %3 quad_perm:[2,3,0,1] row_mask:0xf bank_mask:0xf\n\t"
        "v_add_f32_dpp %0, %0, %0 row_half_mirror row_mask:0xf bank_mask:0xf\n\t"
        "v_add_f32_dpp %1, %1, %1 row_half_mirror row_mask:0xf bank_mask:0xf\n\t"
        "v_add_f32_dpp %2, %2, %2 row_half_mirror row_mask:0xf bank_mask:0xf\n\t"
        "v_add_f32_dpp %3, %3, %3 row_half_mirror row_mask:0xf bank_mask:0xf\n\t"
        "v_add_f32_dpp %0, %0, %0 row_mirror row_mask:0xf bank_mask:0xf\n\t"
        "v_add_f32_dpp %1, %1, %1 row_mirror row_mask:0xf bank_mask:0xf\n\t"
        "v_add_f32_dpp %2, %2, %2 row_mirror row_mask:0xf bank_mask:0xf\n\t"
        "v_add_f32_dpp %3, %3, %3 row_mirror row_mask:0xf bank_mask:0xf\n\t"
        "v_add_f32_dpp %0, %0, %0 row_bcast:15 row_mask:0xf bank_mask:0xf\n\t"
        "v_add_f32_dpp %1, %1, %1 row_bcast:15 row_mask:0xf bank_mask:0xf\n\t"
        "v_add_f32_dpp %2, %2, %2 row_bcast:15 row_mask:0xf bank_mask:0xf\n\t"
        "v_add_f32_dpp %3, %3, %3 row_bcast:15 row_mask:0xf bank_mask:0xf\n\t"
        "v_add_f32_dpp %0, %0, %0 row_bcast:31 row_mask:0xf bank_mask:0xf\n\t"
        "v_add_f32_dpp %1, %1, %1 row_bcast:31 row_mask:0xf bank_mask:0xf\n\t"
        "v_add_f32_dpp %2, %2, %2 row_bcast:31 row_mask:0xf bank_mask:0xf\n\t"
        "v_add_f32_dpp %3, %3, %3 row_bcast:31 row_mask:0xf bank_mask:0xf"
        : "+v"(p0), "+v"(p1), "+v"(p2), "+v"(p3));
}

// LDS-only barrier: drain LDS ops, sync waves. Does NOT drain vmcnt — global
// stores/prefetches stay in flight across it.
__device__ __forceinline__ void lds_barrier() {
    asm volatile("s_waitcnt lgkmcnt(0)\n\ts_barrier" ::: "memory");
}

__global__ __launch_bounds__(256, 1) void qlstm_kernel(
    const float* __restrict__ x,      // [B,T,F]
    const float* __restrict__ W_in,   // [H+F, 4] (row = float4)
    const float* __restrict__ b_in,   // [4]
    const float* __restrict__ Wq,     // [4,4,4]
    const float* __restrict__ bq,     // [4,4]
    const float* __restrict__ W_out,  // [4,H]
    const float* __restrict__ b_out,  // [H]
    float* __restrict__ out)          // [B*T*H] ++ [B*H] ++ [B*H]
{
    const int b = blockIdx.x;
    const int g = threadIdx.x;   // 0..255 — my h index
    const int w = g >> 6;        // wave 0..3
    const int l = g & 63;

    __shared__ float4 part[2][4];  // [slot][wave] y-partials

    const float4* Win4 = (const float4*)W_in;

    float4 t4 = Win4[g];
    float wh[4] = {t4.x, t4.y, t4.z, t4.w};

    const bool has_x = (w < 2);
    float wx[4] = {0.f, 0.f, 0.f, 0.f};
    if (has_x) {
        float4 u4 = Win4[H_ + g];
        wx[0] = u4.x; wx[1] = u4.y; wx[2] = u4.z; wx[3] = u4.w;
    }

    // Per-gate pre-scaled W_out columns / b_out.
    const float sk[4] = {-SC1, -SC1, SC2, -SC1};
    float wo_k[4][4];
    float bo_k[4];
    {
        const float bo = b_out[g];
#pragma unroll
        for (int r = 0; r < 4; ++r) {
            const float wor = W_out[r * H_ + g];
#pragma unroll
            for (int k = 0; k < 4; ++k) wo_k[k][r] = wor * sk[k];
        }
#pragma unroll
        for (int k = 0; k < 4; ++k) bo_k[k] = bo * sk[k];
    }

    float bin[4];
#pragma unroll
    for (int q = 0; q < 4; ++q) bin[q] = b_in[q];

    // Lane-distributed q-block (pre-scaled by SC2).
    const int m = l & 15, qk = m >> 2, qr = m & 3;
    float wql[4];
#pragma unroll
    for (int s = 0; s < 4; ++s) wql[s] = Wq[qk * 16 + s * 4 + qr];
    float bql = bq[qk * 4 + qr];
#pragma unroll
    for (int s = 0; s < 4; ++s) bql = fmaf(bin[s], wql[s], bql);
    bql *= SC2;
#pragma unroll
    for (int s = 0; s < 4; ++s) wql[s] *= SC2;

    float h = 0.f;
    float C = 0.f;   // scaled cell state: C = SC2 * c

    const float* xp = x + (size_t)b * T_ * F_ + g;
    // Software-pipelined x: xq = x(t)*wx (consumed at step t top),
    // xv1 = x(t+1) value; a load of x(t+2) is issued in step t's window.
    float xq0 = 0.f, xq1 = 0.f, xq2 = 0.f, xq3 = 0.f;
    float xv1 = 0.f;
    if (has_x) {
        const float xv0 = xp[0];
        xv1 = xp[F_];
        xq0 = xv0 * wx[0]; xq1 = xv0 * wx[1];
        xq2 = xv0 * wx[2]; xq3 = xv0 * wx[3];
    }

    float* outp = out + (size_t)b * T_ * H_ + g;

#define STEP(t, slot)                                                          \
    {                                                                          \
        float p0 = fmaf(h, wh[0], xq0);                                        \
        float p1 = fmaf(h, wh[1], xq1);                                        \
        float p2 = fmaf(h, wh[2], xq2);                                        \
        float p3 = fmaf(h, wh[3], xq3);                                        \
        tree4(p0, p1, p2, p3);                                                 \
        if (l == 63) part[slot][w] = make_float4(p0, p1, p2, p3);              \
        lds_barrier();                                                         \
        const float4 a0 = part[slot][0];                                       \
        const float4 a1 = part[slot][1];                                       \
        const float4 a2 = part[slot][2];                                       \
        const float4 a3 = part[slot][3];                                       \
        /* window filler: next step's x products + prefetch (y-independent) */ \
        if (has_x) {                                                           \
            xq0 = xv1 * wx[0]; xq1 = xv1 * wx[1];                              \
            xq2 = xv1 * wx[2]; xq3 = xv1 * wx[3];                              \
            int tn = (t) + 2; if (tn >= T_) tn = T_ - 1;                       \
            xv1 = xp[(size_t)tn * F_];                                         \
        }                                                                      \
        const f2 y01 = (mk2(a0.x, a0.y) + mk2(a1.x, a1.y)) +                   \
                       (mk2(a2.x, a2.y) + mk2(a3.x, a3.y));                    \
        const f2 y23 = (mk2(a0.z, a0.w) + mk2(a1.z, a1.w)) +                   \
                       (mk2(a2.z, a2.w) + mk2(a3.z, a3.w));                    \
        float u = fmaf(y01.x, wql[0], bql);                                    \
        const float vv = fmaf(y23.x, wql[2], y01.y * wql[1]);                  \
        u = fmaf(y23.y, wql[3], u);                                            \
        const float aq = u + vv;                                               \
        const float qown = 1.0f - 2.0f * rcp_f(1.0f + exp2_f(aq));             \
        float qs[16];                                                          \
        _Pragma("unroll")                                                      \
        for (int i = 0; i < 16; ++i) qs[i] = rl(qown, i);                      \
        float zp[4];                                                           \
        _Pragma("unroll")                                                      \
        for (int k = 0; k < 4; ++k) {                                          \
            float a = fmaf(qs[k * 4 + 0], wo_k[k][0], bo_k[k]);                \
            const float bs = fmaf(qs[k * 4 + 1], wo_k[k][1],                   \
                                  qs[k * 4 + 2] * wo_k[k][2]);                 \
            a = fmaf(qs[k * 4 + 3], wo_k[k][3], a);                            \
            zp[k] = a + bs;                                                    \
        }                                                                      \
        const float e0 = exp2_f(zp[0]);                                        \
        const float e1 = exp2_f(zp[1]);                                        \
        const float E2 = exp2_f(zp[2]);                                        \
        const float e3 = exp2_f(zp[3]);                                        \
        const float num2 = fmaf(SC2, E2, -SC2);                                \
        const float IG2  = num2 * rcp_f((1.0f + e0) * (1.0f + E2));            \
        const float fg   = rcp_f(1.0f + e1);                                   \
        C = fmaf(fg, C, IG2);                                                  \
        const float Ec = exp2_f(C);                                            \
        h = (Ec - 1.0f) * rcp_f((1.0f + e3) * (1.0f + Ec));                    \
        outp[(size_t)(t) * H_] = h;                                            \
    }

    for (int t = 0; t < T_; t += 2) {
        STEP(t, 0);
        STEP(t + 1, 1);
    }
#undef STEP

    float* hT = out + (size_t)B_ * T_ * H_;
    hT[(size_t)b * H_ + g] = h;
    hT[(size_t)B_ * H_ + (size_t)b * H_ + g] = C * ISC2;
}

extern "C" void kernel_launch(void* const* d_in, const int* in_sizes, int n_in,
                              void* d_out, int out_size, void* d_ws, size_t ws_size,
                              hipStream_t stream) {
    const float* x     = (const float*)d_in[0];
    const float* W_in  = (const float*)d_in[1];
    const float* b_in  = (const float*)d_in[2];
    const float* Wq    = (const float*)d_in[3];
    const float* bq    = (const float*)d_in[4];
    const float* W_out = (const float*)d_in[5];
    const float* b_out = (const float*)d_in[6];
    float* out = (float*)d_out;

    qlstm_kernel<<<dim3(B_), dim3(256), 0, stream>>>(
        x, W_in, b_in, Wq, bq, W_out, b_out, out);
}